// Round 4
// baseline (2229.640 us; speedup 1.0000x reference)
//
#include <hip/hip_runtime.h>
#include <hip/hip_bf16.h>

#define N_NODES 50000
#define N_EDGES 400000
#define N_GRAPH 256
#define HID 256
#define DEPTH 6

typedef float f32x4 __attribute__((ext_vector_type(4)));
typedef int   i32x4 __attribute__((ext_vector_type(4)));

__device__ __forceinline__ float bf2f(unsigned short u) {
  unsigned v = ((unsigned)u) << 16;
  return __builtin_bit_cast(float, v);
}
__device__ __forceinline__ unsigned short f2bf(float f) {
  unsigned u = __builtin_bit_cast(unsigned, f);
  u += 0x7fffu + ((u >> 16) & 1u);  // RNE
  return (unsigned short)(u >> 16);
}

__device__ __forceinline__ float block_sum256(float v, float* lds) {
#pragma unroll
  for (int off = 32; off > 0; off >>= 1) v += __shfl_down(v, off, 64);
  int w = threadIdx.x >> 6;
  if ((threadIdx.x & 63) == 0) lds[w] = v;
  __syncthreads();
  float r = lds[0] + lds[1] + lds[2] + lds[3];
  __syncthreads();
  return r;
}

__global__ __launch_bounds__(256) void k_deg(const int* __restrict__ src, const int* __restrict__ dst,
                                             int* deg_out, int* deg_in) {
  int e = blockIdx.x * 256 + threadIdx.x;
  if (e < N_EDGES) { atomicAdd(&deg_out[src[e]], 1); atomicAdd(&deg_in[dst[e]], 1); }
}

__global__ __launch_bounds__(256) void k_norm(const int* deg_out, const int* deg_in,
                                              float* norm_o, float* norm_i) {
  int i = blockIdx.x * 256 + threadIdx.x;
  if (i < N_NODES) {
    int dO = deg_out[i], dI = deg_in[i];
    norm_o[i] = dO > 0 ? rsqrtf((float)dO) : 0.f;
    norm_i[i] = dI > 0 ? rsqrtf((float)dI) : 0.f;
  }
}

__global__ __launch_bounds__(256) void k_scan1(const int* deg_in, int* partial) {
  int i = blockIdx.x * 256 + threadIdx.x;
  int v = (i < N_NODES) ? deg_in[i] : 0;
#pragma unroll
  for (int off = 32; off > 0; off >>= 1) v += __shfl_down(v, off, 64);
  __shared__ int l[4];
  if ((threadIdx.x & 63) == 0) l[threadIdx.x >> 6] = v;
  __syncthreads();
  if (threadIdx.x == 0) partial[blockIdx.x] = l[0] + l[1] + l[2] + l[3];
}

__global__ __launch_bounds__(256) void k_scan2(const int* partial, int* chunk_off, int* row_start, int nb) {
  __shared__ int ss[256];
  int t = threadIdx.x;
  int v = (t < nb) ? partial[t] : 0;
  ss[t] = v; __syncthreads();
#pragma unroll
  for (int off = 1; off < 256; off <<= 1) {
    int x = ss[t];
    int y = (t >= off) ? ss[t - off] : 0;
    __syncthreads();
    ss[t] = x + y;
    __syncthreads();
  }
  if (t < nb) chunk_off[t] = ss[t] - v;
  if (t == 0) row_start[N_NODES] = N_EDGES;
}

__global__ __launch_bounds__(256) void k_scan3(const int* deg_in, const int* chunk_off, int* row_start) {
  __shared__ int ss[256];
  int t = threadIdx.x;
  int i = blockIdx.x * 256 + t;
  int v = (i < N_NODES) ? deg_in[i] : 0;
  ss[t] = v; __syncthreads();
#pragma unroll
  for (int off = 1; off < 256; off <<= 1) {
    int x = ss[t];
    int y = (t >= off) ? ss[t - off] : 0;
    __syncthreads();
    ss[t] = x + y;
    __syncthreads();
  }
  if (i < N_NODES) row_start[i] = chunk_off[blockIdx.x] + ss[t] - v;
}

__global__ __launch_bounds__(256) void k_fill(const int* src, const int* dst, const int* row_start,
                                              int* cursor, int* csr_src, int* csr_eid) {
  int e = blockIdx.x * 256 + threadIdx.x;
  if (e < N_EDGES) {
    int d = dst[e];
    int p = atomicAdd(&cursor[d], 1);
    int pos = row_start[d] + p;
    csr_src[pos] = src[e];
    csr_eid[pos] = e;
  }
}

// Transpose + bf16-convert all 12 layer weights: Wt[li][n][k] = W[li][k][n]
__global__ __launch_bounds__(256) void k_wt(const float* __restrict__ Wc1, const float* __restrict__ Wc2,
                                            unsigned short* __restrict__ Wt) {
  __shared__ float tile[32][33];
  int li = blockIdx.z;
  const float* W = ((li & 1) ? Wc2 : Wc1) + (size_t)(li >> 1) * HID * HID;
  int k0 = blockIdx.x * 32, n0 = blockIdx.y * 32;
  int tx = threadIdx.x & 31, ty = threadIdx.x >> 5;
#pragma unroll
  for (int r = ty; r < 32; r += 8) tile[r][tx] = W[(size_t)(k0 + r) * HID + n0 + tx];
  __syncthreads();
  unsigned short* outp = Wt + (size_t)li * HID * HID;
#pragma unroll
  for (int r = ty; r < 32; r += 8) outp[(size_t)(n0 + r) * HID + k0 + tx] = f2bf(tile[tx][r]);
}

// Pack z[n][32] = concat(a,c,x)[27] * norm_o[n]  (pad to 32 f32)
__global__ __launch_bounds__(256) void k_z(const float* __restrict__ a, const float* __restrict__ c,
                                           const float* __restrict__ x, const float* __restrict__ norm_o,
                                           float* __restrict__ z) {
  int t = blockIdx.x * 256 + threadIdx.x;
  int n = t >> 5, lane = t & 31;
  if (n >= N_NODES) return;
  float v = 0.f;
  if (lane < 16) v = a[(size_t)n * 16 + lane];
  else if (lane < 24) v = c[(size_t)n * 8 + (lane - 16)];
  else if (lane < 27) v = x[(size_t)n * 3 + (lane - 24)];
  z[(size_t)n * 32 + lane] = v * norm_o[n];
}

// Input layer fused: aggregate packed z rows + e_t rows per node, K=43 matvec,
// produce hf (f32 residual stream) and Af (bf16 next-A).
__global__ __launch_bounds__(256) void k_in(const float* __restrict__ z, const float* __restrict__ e_t,
                                            const int* __restrict__ csr_src, const int* __restrict__ csr_eid,
                                            const int* __restrict__ rs, const float* __restrict__ norm_o,
                                            const float* __restrict__ norm_i, const float* __restrict__ W_in,
                                            const float* __restrict__ b_in, const float* __restrict__ W_e,
                                            const float* __restrict__ b_e, float* __restrict__ hf,
                                            unsigned short* __restrict__ Af) {
  int w = threadIdx.x >> 6, lane = threadIdx.x & 63;
  int n = blockIdx.x * 4 + w;  // 50000 % 4 == 0
  __shared__ float zs[4][48];
  int beg = rs[n], end = rs[n + 1];
  float acc = 0.f;
  for (int p = beg; p < end; ++p) {
    if (lane < 27) acc += z[(size_t)csr_src[p] * 32 + lane];
    else if (lane >= 32 && lane < 48) acc += e_t[(size_t)csr_eid[p] * 16 + (lane - 32)];
  }
  if (lane < 27) zs[w][lane] = acc;
  else if (lane >= 32 && lane < 48) zs[w][27 + lane - 32] = acc;
  __syncthreads();
  float degf = (float)(end - beg);
  float invd = 1.f / fmaxf(degf, 1.f);
  float niv = norm_i[n], nov = norm_o[n];
#pragma unroll
  for (int i = 0; i < 4; ++i) {
    int ch = lane + 64 * i;
    float da = 0.f, de = 0.f;
#pragma unroll
    for (int k = 0; k < 27; ++k) da += zs[w][k] * W_in[k * HID + ch];
#pragma unroll
    for (int k = 0; k < 16; ++k) de += zs[w][27 + k] * W_e[k * HID + ch];
    float val = da * niv + b_in[ch] + (de + degf * b_e[ch]) * invd;
    hf[(size_t)n * HID + ch] = val;
    Af[(size_t)n * HID + ch] = f2bf(val * nov);
  }
}

// Fused layer: per-block gather 64 node rows (neighbor bf16 sums from Af) into LDS,
// MFMA GEMM [64,256]@[256,256], epilogue norm_i+b -> LN -> SiLU -> (+res) -> AfN.
// Af and AfN MUST be distinct buffers (inter-block WAR race otherwise — R3 bug).
template <int RES>
__global__ __launch_bounds__(256) void k_layer(const unsigned short* __restrict__ Af,
                                               const int* __restrict__ csr_src, const int* __restrict__ rs,
                                               const unsigned short* __restrict__ Bt,
                                               const float* __restrict__ norm_i,
                                               const float* __restrict__ norm_o,
                                               const float* __restrict__ b, const float* __restrict__ g,
                                               const float* __restrict__ be, float* __restrict__ hf,
                                               unsigned short* __restrict__ AfN) {
  const int M = N_NODES;
  const int LDA = HID + 8;  // +16B pad: A-frag ds_read_b128 rows land 2-way (free)
  __shared__ unsigned short As[64 * LDA];
  int wave = threadIdx.x >> 6, lane = threadIdx.x & 63;
  int l15 = lane & 15, quad = lane >> 4;
  int row0 = blockIdx.x * 64 + wave * 16;
  int off = lane * 4;
  // ---- gather phase: this wave fills rows [wave*16, wave*16+16) of As ----
  for (int i = 0; i < 16; ++i) {
    int n = row0 + i;
    int nc = n < M ? n : M - 1;  // clamped rows produce garbage, never stored
    int beg = rs[nc], end = rs[nc + 1];
    float a0 = 0.f, a1 = 0.f, a2 = 0.f, a3 = 0.f;
    int p = beg;
    for (; p + 4 <= end; p += 4) {
      int s0 = csr_src[p], s1 = csr_src[p + 1], s2 = csr_src[p + 2], s3 = csr_src[p + 3];
      ushort4 r0 = *(const ushort4*)(Af + (size_t)s0 * HID + off);
      ushort4 r1 = *(const ushort4*)(Af + (size_t)s1 * HID + off);
      ushort4 r2 = *(const ushort4*)(Af + (size_t)s2 * HID + off);
      ushort4 r3 = *(const ushort4*)(Af + (size_t)s3 * HID + off);
      a0 += bf2f(r0.x) + bf2f(r1.x) + bf2f(r2.x) + bf2f(r3.x);
      a1 += bf2f(r0.y) + bf2f(r1.y) + bf2f(r2.y) + bf2f(r3.y);
      a2 += bf2f(r0.z) + bf2f(r1.z) + bf2f(r2.z) + bf2f(r3.z);
      a3 += bf2f(r0.w) + bf2f(r1.w) + bf2f(r2.w) + bf2f(r3.w);
    }
    for (; p < end; ++p) {
      int s0 = csr_src[p];
      ushort4 r0 = *(const ushort4*)(Af + (size_t)s0 * HID + off);
      a0 += bf2f(r0.x); a1 += bf2f(r0.y); a2 += bf2f(r0.z); a3 += bf2f(r0.w);
    }
    ushort4 o;
    o.x = f2bf(a0); o.y = f2bf(a1); o.z = f2bf(a2); o.w = f2bf(a3);
    *(ushort4*)(&As[(size_t)(wave * 16 + i) * LDA + off]) = o;
  }
  __syncthreads();  // LDS write -> ds_read visibility (cheap, removes ordering doubt)
  // ---- GEMM phase ----
  const unsigned short* bp = Bt + (size_t)l15 * HID + quad * 8;
  const unsigned short* asp = &As[(size_t)(wave * 16 + l15) * LDA + quad * 8];
  f32x4 acc[16] = {};
  asm volatile("s_nop 7\n\ts_nop 7"
               : "+v"(acc[0]), "+v"(acc[1]), "+v"(acc[2]), "+v"(acc[3]),
                 "+v"(acc[4]), "+v"(acc[5]), "+v"(acc[6]), "+v"(acc[7]),
                 "+v"(acc[8]), "+v"(acc[9]), "+v"(acc[10]), "+v"(acc[11]),
                 "+v"(acc[12]), "+v"(acc[13]), "+v"(acc[14]), "+v"(acc[15]));
#pragma unroll
  for (int k0 = 0; k0 < HID; k0 += 32) {
    i32x4 af = *(const i32x4*)(asp + k0);
#pragma unroll
    for (int t = 0; t < 16; ++t) {
      i32x4 bt = *(const i32x4*)(bp + (size_t)t * 16 * HID + k0);
      asm volatile("v_mfma_f32_16x16x32_bf16 %0, %1, %2, %0" : "+v"(acc[t]) : "v"(af), "v"(bt));
    }
  }
  asm volatile("s_nop 7\n\ts_nop 7\n\ts_nop 7"
               : "+v"(acc[0]), "+v"(acc[1]), "+v"(acc[2]), "+v"(acc[3]),
                 "+v"(acc[4]), "+v"(acc[5]), "+v"(acc[6]), "+v"(acc[7]),
                 "+v"(acc[8]), "+v"(acc[9]), "+v"(acc[10]), "+v"(acc[11]),
                 "+v"(acc[12]), "+v"(acc[13]), "+v"(acc[14]), "+v"(acc[15]));
  // epilogue: rows r = row0 + quad*4 + j, cols ct = t*16 + l15
  float ni[4], no[4];
#pragma unroll
  for (int j = 0; j < 4; ++j) {
    int r = row0 + quad * 4 + j;
    int rc = r < M ? r : M - 1;
    ni[j] = norm_i[rc];
    no[j] = norm_o[rc];
  }
#pragma unroll
  for (int t = 0; t < 16; ++t) {
    int ct = t * 16 + l15;
    float bv = b[ct];
#pragma unroll
    for (int j = 0; j < 4; ++j) acc[t][j] = acc[t][j] * ni[j] + bv;
  }
  float s1[4] = {0.f, 0.f, 0.f, 0.f}, s2[4] = {0.f, 0.f, 0.f, 0.f};
#pragma unroll
  for (int t = 0; t < 16; ++t)
#pragma unroll
    for (int j = 0; j < 4; ++j) { s1[j] += acc[t][j]; s2[j] += acc[t][j] * acc[t][j]; }
#pragma unroll
  for (int m = 1; m < 16; m <<= 1) {
#pragma unroll
    for (int j = 0; j < 4; ++j) {
      s1[j] += __shfl_xor(s1[j], m, 16);
      s2[j] += __shfl_xor(s2[j], m, 16);
    }
  }
  float mu[4], inv[4];
#pragma unroll
  for (int j = 0; j < 4; ++j) {
    mu[j] = s1[j] * (1.f / HID);
    float var = s2[j] * (1.f / HID) - mu[j] * mu[j];
    inv[j] = rsqrtf(var + 1e-5f);
  }
#pragma unroll
  for (int j = 0; j < 4; ++j) {
    int r = row0 + quad * 4 + j;
    if (r < M) {
      float* hrow = hf + (size_t)r * HID;
      unsigned short* an = AfN + (size_t)r * HID;
#pragma unroll
      for (int t = 0; t < 16; ++t) {
        int ct = t * 16 + l15;
        float o = (acc[t][j] - mu[j]) * inv[j] * g[ct] + be[ct];
        float sl = o * (1.f / (1.f + __expf(-o)));
        float outv = sl;
        if (RES) {
          outv = sl + hrow[ct];
          hrow[ct] = outv;
        }
        an[ct] = f2bf(outv * no[j]);
      }
    }
  }
}

// Fused mean-pool + head, no atomics: gid is sorted, one block per graph,
// binary-search the segment, stream rows, dot with W_head, softplus.
__global__ __launch_bounds__(256) void k_poolhead(const float* __restrict__ hf, const int* __restrict__ gid,
                                                  const float* __restrict__ Wh, const float* __restrict__ bh,
                                                  float* __restrict__ out) {
  int gg = blockIdx.x, ch = threadIdx.x;
  int lo = 0, hi = N_NODES;
  while (lo < hi) { int mid = (lo + hi) >> 1; if (gid[mid] < gg) lo = mid + 1; else hi = mid; }
  int beg = lo;
  hi = N_NODES;
  while (lo < hi) { int mid = (lo + hi) >> 1; if (gid[mid] < gg + 1) lo = mid + 1; else hi = mid; }
  int end = lo;
  float s = 0.f;
  int n = beg;
  for (; n + 4 <= end; n += 4) {
    s += hf[(size_t)n * HID + ch] + hf[(size_t)(n + 1) * HID + ch] +
         hf[(size_t)(n + 2) * HID + ch] + hf[(size_t)(n + 3) * HID + ch];
  }
  for (; n < end; ++n) s += hf[(size_t)n * HID + ch];
  float v = s * Wh[ch];
  __shared__ float l[4];
  float tot = block_sum256(v, l);
  if (ch == 0) {
    float c = fmaxf((float)(end - beg), 1.f);
    float xx = tot / c + bh[0];
    out[gg] = fmaxf(xx, 0.f) + log1pf(expf(-fabsf(xx)));  // stable softplus
  }
}

extern "C" void kernel_launch(void* const* d_in, const int* in_sizes, int n_in,
                              void* d_out, int out_size, void* d_ws, size_t ws_size,
                              hipStream_t stream) {
  const float* a_t = (const float*)d_in[0];
  const float* c_t = (const float*)d_in[1];
  const float* x_t = (const float*)d_in[2];
  const float* e_t = (const float*)d_in[3];
  const int* src = (const int*)d_in[4];
  const int* dst = (const int*)d_in[5];
  const int* gid = (const int*)d_in[6];
  const float* W_in = (const float*)d_in[7];
  const float* b_in = (const float*)d_in[8];
  const float* W_e  = (const float*)d_in[9];
  const float* b_e  = (const float*)d_in[10];
  const float* Wc1  = (const float*)d_in[11];
  const float* bc1  = (const float*)d_in[12];
  const float* g1   = (const float*)d_in[13];
  const float* be1  = (const float*)d_in[14];
  const float* Wc2  = (const float*)d_in[15];
  const float* bc2  = (const float*)d_in[16];
  const float* g2   = (const float*)d_in[17];
  const float* be2  = (const float*)d_in[18];
  const float* W_head = (const float*)d_in[19];
  const float* b_head = (const float*)d_in[20];
  float* out = (float*)d_out;

  char* base = (char*)d_ws;
  size_t off = 0;
  auto carve = [&](size_t bytes) -> void* {
    void* p = base + off;
    off += (bytes + 255) & ~(size_t)255;
    return p;
  };
  int*   deg_out = (int*)carve((size_t)N_NODES * 4);
  int*   deg_in  = (int*)carve((size_t)N_NODES * 4);
  int*   cursor  = (int*)carve((size_t)N_NODES * 4);
  size_t zbytes = off;  // zeroed each call
  float* norm_o  = (float*)carve((size_t)N_NODES * 4);
  float* norm_i  = (float*)carve((size_t)N_NODES * 4);
  int*   row_start = (int*)carve((size_t)(N_NODES + 1) * 4);
  int*   partial   = (int*)carve(256 * 4);
  int*   chunk_off = (int*)carve(256 * 4);
  int*   csr_src   = (int*)carve((size_t)N_EDGES * 4);
  int*   csr_eid   = (int*)carve((size_t)N_EDGES * 4);
  unsigned short* Wt = (unsigned short*)carve((size_t)2 * DEPTH * HID * HID * 2);
  float* zpack = (float*)carve((size_t)N_NODES * 32 * 4);
  float* hf = (float*)carve((size_t)N_NODES * HID * 4);
  unsigned short* Af0 = (unsigned short*)carve((size_t)N_NODES * HID * 2);
  unsigned short* Af1 = (unsigned short*)carve((size_t)N_NODES * HID * 2);
  (void)ws_size; (void)in_sizes; (void)n_in; (void)out_size;

  hipMemsetAsync(d_ws, 0, zbytes, stream);

  int ebl = (N_EDGES + 255) / 256;
  int nbl = (N_NODES + 255) / 256;
  k_deg<<<ebl, 256, 0, stream>>>(src, dst, deg_out, deg_in);
  k_norm<<<nbl, 256, 0, stream>>>(deg_out, deg_in, norm_o, norm_i);
  k_scan1<<<nbl, 256, 0, stream>>>(deg_in, partial);
  k_scan2<<<1, 256, 0, stream>>>(partial, chunk_off, row_start, nbl);
  k_scan3<<<nbl, 256, 0, stream>>>(deg_in, chunk_off, row_start);
  k_fill<<<ebl, 256, 0, stream>>>(src, dst, row_start, cursor, csr_src, csr_eid);
  k_wt<<<dim3(8, 8, 2 * DEPTH), 256, 0, stream>>>(Wc1, Wc2, Wt);
  k_z<<<(N_NODES * 32 + 255) / 256, 256, 0, stream>>>(a_t, c_t, x_t, norm_o, zpack);
  k_in<<<N_NODES / 4, 256, 0, stream>>>(zpack, e_t, csr_src, csr_eid, row_start,
                                        norm_o, norm_i, W_in, b_in, W_e, b_e, hf, Af0);
  int gbl = (N_NODES + 63) / 64;  // 782
  for (int d = 0; d < DEPTH; ++d) {
    // ping-pong: Af0 -> Af1 -> Af0 (read and write buffers must differ)
    k_layer<0><<<gbl, 256, 0, stream>>>(Af0, csr_src, row_start, Wt + (size_t)(2 * d) * HID * HID,
                                        norm_i, norm_o, bc1 + d * HID, g1 + d * HID, be1 + d * HID, hf, Af1);
    k_layer<1><<<gbl, 256, 0, stream>>>(Af1, csr_src, row_start, Wt + (size_t)(2 * d + 1) * HID * HID,
                                        norm_i, norm_o, bc2 + d * HID, g2 + d * HID, be2 + d * HID, hf, Af0);
  }
  k_poolhead<<<N_GRAPH, 256, 0, stream>>>(hf, gid, W_head, b_head, out);
}

// Round 5
// 1492.914 us; speedup vs baseline: 1.4935x; 1.4935x over previous
//
#include <hip/hip_runtime.h>
#include <hip/hip_bf16.h>

#define N_NODES 50000
#define N_EDGES 400000
#define N_GRAPH 256
#define HID 256
#define DEPTH 6

typedef float f32x4 __attribute__((ext_vector_type(4)));
typedef int   i32x4 __attribute__((ext_vector_type(4)));

__device__ __forceinline__ float bf2f(unsigned short u) {
  unsigned v = ((unsigned)u) << 16;
  return __builtin_bit_cast(float, v);
}
__device__ __forceinline__ unsigned short f2bf(float f) {
  unsigned u = __builtin_bit_cast(unsigned, f);
  u += 0x7fffu + ((u >> 16) & 1u);  // RNE
  return (unsigned short)(u >> 16);
}

__device__ __forceinline__ float block_sum256(float v, float* lds) {
#pragma unroll
  for (int off = 32; off > 0; off >>= 1) v += __shfl_down(v, off, 64);
  int w = threadIdx.x >> 6;
  if ((threadIdx.x & 63) == 0) lds[w] = v;
  __syncthreads();
  float r = lds[0] + lds[1] + lds[2] + lds[3];
  __syncthreads();
  return r;
}

__global__ __launch_bounds__(256) void k_deg(const int* __restrict__ src, const int* __restrict__ dst,
                                             int* deg_out, int* deg_in) {
  int e = blockIdx.x * 256 + threadIdx.x;
  if (e < N_EDGES) { atomicAdd(&deg_out[src[e]], 1); atomicAdd(&deg_in[dst[e]], 1); }
}

__global__ __launch_bounds__(256) void k_norm(const int* deg_out, const int* deg_in,
                                              float* norm_o, float* norm_i) {
  int i = blockIdx.x * 256 + threadIdx.x;
  if (i < N_NODES) {
    int dO = deg_out[i], dI = deg_in[i];
    norm_o[i] = dO > 0 ? rsqrtf((float)dO) : 0.f;
    norm_i[i] = dI > 0 ? rsqrtf((float)dI) : 0.f;
  }
}

__global__ __launch_bounds__(256) void k_scan1(const int* deg_in, int* partial) {
  int i = blockIdx.x * 256 + threadIdx.x;
  int v = (i < N_NODES) ? deg_in[i] : 0;
#pragma unroll
  for (int off = 32; off > 0; off >>= 1) v += __shfl_down(v, off, 64);
  __shared__ int l[4];
  if ((threadIdx.x & 63) == 0) l[threadIdx.x >> 6] = v;
  __syncthreads();
  if (threadIdx.x == 0) partial[blockIdx.x] = l[0] + l[1] + l[2] + l[3];
}

__global__ __launch_bounds__(256) void k_scan2(const int* partial, int* chunk_off, int* row_start, int nb) {
  __shared__ int ss[256];
  int t = threadIdx.x;
  int v = (t < nb) ? partial[t] : 0;
  ss[t] = v; __syncthreads();
#pragma unroll
  for (int off = 1; off < 256; off <<= 1) {
    int x = ss[t];
    int y = (t >= off) ? ss[t - off] : 0;
    __syncthreads();
    ss[t] = x + y;
    __syncthreads();
  }
  if (t < nb) chunk_off[t] = ss[t] - v;
  if (t == 0) row_start[N_NODES] = N_EDGES;
}

__global__ __launch_bounds__(256) void k_scan3(const int* deg_in, const int* chunk_off, int* row_start) {
  __shared__ int ss[256];
  int t = threadIdx.x;
  int i = blockIdx.x * 256 + t;
  int v = (i < N_NODES) ? deg_in[i] : 0;
  ss[t] = v; __syncthreads();
#pragma unroll
  for (int off = 1; off < 256; off <<= 1) {
    int x = ss[t];
    int y = (t >= off) ? ss[t - off] : 0;
    __syncthreads();
    ss[t] = x + y;
    __syncthreads();
  }
  if (i < N_NODES) row_start[i] = chunk_off[blockIdx.x] + ss[t] - v;
}

__global__ __launch_bounds__(256) void k_fill(const int* src, const int* dst, const int* row_start,
                                              int* cursor, int* csr_src, int* csr_eid) {
  int e = blockIdx.x * 256 + threadIdx.x;
  if (e < N_EDGES) {
    int d = dst[e];
    int p = atomicAdd(&cursor[d], 1);
    int pos = row_start[d] + p;
    csr_src[pos] = src[e];
    csr_eid[pos] = e;
  }
}

// Transpose + bf16-convert all 12 layer weights: Wt[li][n][k] = W[li][k][n]
__global__ __launch_bounds__(256) void k_wt(const float* __restrict__ Wc1, const float* __restrict__ Wc2,
                                            unsigned short* __restrict__ Wt) {
  __shared__ float tile[32][33];
  int li = blockIdx.z;
  const float* W = ((li & 1) ? Wc2 : Wc1) + (size_t)(li >> 1) * HID * HID;
  int k0 = blockIdx.x * 32, n0 = blockIdx.y * 32;
  int tx = threadIdx.x & 31, ty = threadIdx.x >> 5;
#pragma unroll
  for (int r = ty; r < 32; r += 8) tile[r][tx] = W[(size_t)(k0 + r) * HID + n0 + tx];
  __syncthreads();
  unsigned short* outp = Wt + (size_t)li * HID * HID;
#pragma unroll
  for (int r = ty; r < 32; r += 8) outp[(size_t)(n0 + r) * HID + k0 + tx] = f2bf(tile[tx][r]);
}

// Pack z[n][32] = concat(a,c,x)[27] * norm_o[n]  (pad to 32 f32)
__global__ __launch_bounds__(256) void k_z(const float* __restrict__ a, const float* __restrict__ c,
                                           const float* __restrict__ x, const float* __restrict__ norm_o,
                                           float* __restrict__ z) {
  int t = blockIdx.x * 256 + threadIdx.x;
  int n = t >> 5, lane = t & 31;
  if (n >= N_NODES) return;
  float v = 0.f;
  if (lane < 16) v = a[(size_t)n * 16 + lane];
  else if (lane < 24) v = c[(size_t)n * 8 + (lane - 16)];
  else if (lane < 27) v = x[(size_t)n * 3 + (lane - 24)];
  z[(size_t)n * 32 + lane] = v * norm_o[n];
}

// Input layer fused: aggregate packed z rows + e_t rows per node, K=43 matvec,
// produce hf (f32 residual stream) and Af (bf16 next-A).
__global__ __launch_bounds__(256) void k_in(const float* __restrict__ z, const float* __restrict__ e_t,
                                            const int* __restrict__ csr_src, const int* __restrict__ csr_eid,
                                            const int* __restrict__ rs, const float* __restrict__ norm_o,
                                            const float* __restrict__ norm_i, const float* __restrict__ W_in,
                                            const float* __restrict__ b_in, const float* __restrict__ W_e,
                                            const float* __restrict__ b_e, float* __restrict__ hf,
                                            unsigned short* __restrict__ Af) {
  int w = threadIdx.x >> 6, lane = threadIdx.x & 63;
  int n = blockIdx.x * 4 + w;  // 50000 % 4 == 0
  __shared__ float zs[4][48];
  int beg = rs[n], end = rs[n + 1];
  float acc = 0.f;
  for (int p = beg; p < end; ++p) {
    if (lane < 27) acc += z[(size_t)csr_src[p] * 32 + lane];
    else if (lane >= 32 && lane < 48) acc += e_t[(size_t)csr_eid[p] * 16 + (lane - 32)];
  }
  if (lane < 27) zs[w][lane] = acc;
  else if (lane >= 32 && lane < 48) zs[w][27 + lane - 32] = acc;
  __syncthreads();
  float degf = (float)(end - beg);
  float invd = 1.f / fmaxf(degf, 1.f);
  float niv = norm_i[n], nov = norm_o[n];
#pragma unroll
  for (int i = 0; i < 4; ++i) {
    int ch = lane + 64 * i;
    float da = 0.f, de = 0.f;
#pragma unroll
    for (int k = 0; k < 27; ++k) da += zs[w][k] * W_in[k * HID + ch];
#pragma unroll
    for (int k = 0; k < 16; ++k) de += zs[w][27 + k] * W_e[k * HID + ch];
    float val = da * niv + b_in[ch] + (de + degf * b_e[ch]) * invd;
    hf[(size_t)n * HID + ch] = val;
    Af[(size_t)n * HID + ch] = f2bf(val * nov);
  }
}

// Fused layer, 16-row tile (grid 3125): each wave gathers 4 node rows into LDS,
// then computes the 64-col slice of the [16,256]@[256,256] GEMM; epilogue
// norm_i+b -> LN (cross-wave LDS reduce) -> SiLU -> (+res) -> AfN = bf16(out*norm_o).
// Af / AfN must be distinct buffers (inter-block WAR race).
template <int RES>
__global__ __launch_bounds__(256) void k_layer(const unsigned short* __restrict__ Af,
                                               const int* __restrict__ csr_src, const int* __restrict__ rs,
                                               const unsigned short* __restrict__ Bt,
                                               const float* __restrict__ norm_i,
                                               const float* __restrict__ norm_o,
                                               const float* __restrict__ b, const float* __restrict__ g,
                                               const float* __restrict__ be, float* __restrict__ hf,
                                               unsigned short* __restrict__ AfN) {
  const int LDA = HID + 8;  // pad: keeps ds_read_b128 A-frags at <=2-way (free)
  __shared__ unsigned short As[16 * LDA];
  __shared__ float red1[4][16], red2[4][16];
  int wave = threadIdx.x >> 6, lane = threadIdx.x & 63;
  int l15 = lane & 15, quad = lane >> 4;
  int n0 = blockIdx.x * 16;  // 50000 = 16 * 3125, exact
  int off = lane * 4;
  // ---- gather: wave fills rows [wave*4, wave*4+4) of As ----
  for (int i = 0; i < 4; ++i) {
    int r = wave * 4 + i;
    int beg = rs[n0 + r], end = rs[n0 + r + 1];
    float a0 = 0.f, a1 = 0.f, a2 = 0.f, a3 = 0.f;
    int p = beg;
    for (; p + 4 <= end; p += 4) {
      int s0 = csr_src[p], s1 = csr_src[p + 1], s2 = csr_src[p + 2], s3 = csr_src[p + 3];
      ushort4 r0 = *(const ushort4*)(Af + (size_t)s0 * HID + off);
      ushort4 r1 = *(const ushort4*)(Af + (size_t)s1 * HID + off);
      ushort4 r2 = *(const ushort4*)(Af + (size_t)s2 * HID + off);
      ushort4 r3 = *(const ushort4*)(Af + (size_t)s3 * HID + off);
      a0 += bf2f(r0.x) + bf2f(r1.x) + bf2f(r2.x) + bf2f(r3.x);
      a1 += bf2f(r0.y) + bf2f(r1.y) + bf2f(r2.y) + bf2f(r3.y);
      a2 += bf2f(r0.z) + bf2f(r1.z) + bf2f(r2.z) + bf2f(r3.z);
      a3 += bf2f(r0.w) + bf2f(r1.w) + bf2f(r2.w) + bf2f(r3.w);
    }
    for (; p < end; ++p) {
      int s0 = csr_src[p];
      ushort4 r0 = *(const ushort4*)(Af + (size_t)s0 * HID + off);
      a0 += bf2f(r0.x); a1 += bf2f(r0.y); a2 += bf2f(r0.z); a3 += bf2f(r0.w);
    }
    ushort4 o;
    o.x = f2bf(a0); o.y = f2bf(a1); o.z = f2bf(a2); o.w = f2bf(a3);
    *(ushort4*)(&As[(size_t)r * LDA + off]) = o;
  }
  __syncthreads();
  // ---- GEMM: wave covers cols [wave*64, wave*64+64), rows n0..n0+15 ----
  const unsigned short* asp = &As[(size_t)l15 * LDA + quad * 8];
  const unsigned short* bp = Bt + (size_t)(wave * 64 + l15) * HID + quad * 8;
  f32x4 acc[4] = {};
  asm volatile("s_nop 7\n\ts_nop 7" : "+v"(acc[0]), "+v"(acc[1]), "+v"(acc[2]), "+v"(acc[3]));
#pragma unroll
  for (int k0 = 0; k0 < HID; k0 += 32) {
    i32x4 af = *(const i32x4*)(asp + k0);
#pragma unroll
    for (int t = 0; t < 4; ++t) {
      i32x4 bt = *(const i32x4*)(bp + (size_t)t * 16 * HID + k0);
      asm volatile("v_mfma_f32_16x16x32_bf16 %0, %1, %2, %0" : "+v"(acc[t]) : "v"(af), "v"(bt));
    }
  }
  asm volatile("s_nop 7\n\ts_nop 7\n\ts_nop 7"
               : "+v"(acc[0]), "+v"(acc[1]), "+v"(acc[2]), "+v"(acc[3]));
  // C/D layout: col (within slice) = t*16 + l15, row = quad*4 + j
  float ni[4];
#pragma unroll
  for (int j = 0; j < 4; ++j) ni[j] = norm_i[n0 + quad * 4 + j];
#pragma unroll
  for (int t = 0; t < 4; ++t) {
    int ct = wave * 64 + t * 16 + l15;
    float bv = b[ct];
#pragma unroll
    for (int j = 0; j < 4; ++j) acc[t][j] = acc[t][j] * ni[j] + bv;
  }
  float s1[4] = {0.f, 0.f, 0.f, 0.f}, s2[4] = {0.f, 0.f, 0.f, 0.f};
#pragma unroll
  for (int t = 0; t < 4; ++t)
#pragma unroll
    for (int j = 0; j < 4; ++j) { s1[j] += acc[t][j]; s2[j] += acc[t][j] * acc[t][j]; }
#pragma unroll
  for (int m = 1; m < 16; m <<= 1) {
#pragma unroll
    for (int j = 0; j < 4; ++j) {
      s1[j] += __shfl_xor(s1[j], m, 16);
      s2[j] += __shfl_xor(s2[j], m, 16);
    }
  }
  if (l15 == 0) {
#pragma unroll
    for (int j = 0; j < 4; ++j) {
      red1[wave][quad * 4 + j] = s1[j];
      red2[wave][quad * 4 + j] = s2[j];
    }
  }
  __syncthreads();
  float mu[4], inv[4];
#pragma unroll
  for (int j = 0; j < 4; ++j) {
    int r = quad * 4 + j;
    float t1 = red1[0][r] + red1[1][r] + red1[2][r] + red1[3][r];
    float t2 = red2[0][r] + red2[1][r] + red2[2][r] + red2[3][r];
    mu[j] = t1 * (1.f / HID);
    float var = t2 * (1.f / HID) - mu[j] * mu[j];
    inv[j] = rsqrtf(var + 1e-5f);
  }
#pragma unroll
  for (int j = 0; j < 4; ++j) {
    int r = n0 + quad * 4 + j;
    float nov = norm_o[r];
    float* hrow = hf + (size_t)r * HID;
    unsigned short* an = AfN + (size_t)r * HID;
#pragma unroll
    for (int t = 0; t < 4; ++t) {
      int ct = wave * 64 + t * 16 + l15;
      float o = (acc[t][j] - mu[j]) * inv[j] * g[ct] + be[ct];
      float sl = o * (1.f / (1.f + __expf(-o)));
      float outv = sl;
      if (RES) {
        outv = sl + hrow[ct];
        hrow[ct] = outv;
      }
      an[ct] = f2bf(outv * nov);
    }
  }
}

// Fused mean-pool + head, no atomics: gid is sorted, one block per graph.
__global__ __launch_bounds__(256) void k_poolhead(const float* __restrict__ hf, const int* __restrict__ gid,
                                                  const float* __restrict__ Wh, const float* __restrict__ bh,
                                                  float* __restrict__ out) {
  int gg = blockIdx.x, ch = threadIdx.x;
  int lo = 0, hi = N_NODES;
  while (lo < hi) { int mid = (lo + hi) >> 1; if (gid[mid] < gg) lo = mid + 1; else hi = mid; }
  int beg = lo;
  hi = N_NODES;
  while (lo < hi) { int mid = (lo + hi) >> 1; if (gid[mid] < gg + 1) lo = mid + 1; else hi = mid; }
  int end = lo;
  float s = 0.f;
  int n = beg;
  for (; n + 4 <= end; n += 4) {
    s += hf[(size_t)n * HID + ch] + hf[(size_t)(n + 1) * HID + ch] +
         hf[(size_t)(n + 2) * HID + ch] + hf[(size_t)(n + 3) * HID + ch];
  }
  for (; n < end; ++n) s += hf[(size_t)n * HID + ch];
  float v = s * Wh[ch];
  __shared__ float l[4];
  float tot = block_sum256(v, l);
  if (ch == 0) {
    float c = fmaxf((float)(end - beg), 1.f);
    float xx = tot / c + bh[0];
    out[gg] = fmaxf(xx, 0.f) + log1pf(expf(-fabsf(xx)));  // stable softplus
  }
}

extern "C" void kernel_launch(void* const* d_in, const int* in_sizes, int n_in,
                              void* d_out, int out_size, void* d_ws, size_t ws_size,
                              hipStream_t stream) {
  const float* a_t = (const float*)d_in[0];
  const float* c_t = (const float*)d_in[1];
  const float* x_t = (const float*)d_in[2];
  const float* e_t = (const float*)d_in[3];
  const int* src = (const int*)d_in[4];
  const int* dst = (const int*)d_in[5];
  const int* gid = (const int*)d_in[6];
  const float* W_in = (const float*)d_in[7];
  const float* b_in = (const float*)d_in[8];
  const float* W_e  = (const float*)d_in[9];
  const float* b_e  = (const float*)d_in[10];
  const float* Wc1  = (const float*)d_in[11];
  const float* bc1  = (const float*)d_in[12];
  const float* g1   = (const float*)d_in[13];
  const float* be1  = (const float*)d_in[14];
  const float* Wc2  = (const float*)d_in[15];
  const float* bc2  = (const float*)d_in[16];
  const float* g2   = (const float*)d_in[17];
  const float* be2  = (const float*)d_in[18];
  const float* W_head = (const float*)d_in[19];
  const float* b_head = (const float*)d_in[20];
  float* out = (float*)d_out;

  char* base = (char*)d_ws;
  size_t off = 0;
  auto carve = [&](size_t bytes) -> void* {
    void* p = base + off;
    off += (bytes + 255) & ~(size_t)255;
    return p;
  };
  int*   deg_out = (int*)carve((size_t)N_NODES * 4);
  int*   deg_in  = (int*)carve((size_t)N_NODES * 4);
  int*   cursor  = (int*)carve((size_t)N_NODES * 4);
  size_t zbytes = off;  // zeroed each call
  float* norm_o  = (float*)carve((size_t)N_NODES * 4);
  float* norm_i  = (float*)carve((size_t)N_NODES * 4);
  int*   row_start = (int*)carve((size_t)(N_NODES + 1) * 4);
  int*   partial   = (int*)carve(256 * 4);
  int*   chunk_off = (int*)carve(256 * 4);
  int*   csr_src   = (int*)carve((size_t)N_EDGES * 4);
  int*   csr_eid   = (int*)carve((size_t)N_EDGES * 4);
  unsigned short* Wt = (unsigned short*)carve((size_t)2 * DEPTH * HID * HID * 2);
  float* zpack = (float*)carve((size_t)N_NODES * 32 * 4);
  float* hf = (float*)carve((size_t)N_NODES * HID * 4);
  unsigned short* Af0 = (unsigned short*)carve((size_t)N_NODES * HID * 2);
  unsigned short* Af1 = (unsigned short*)carve((size_t)N_NODES * HID * 2);
  (void)ws_size; (void)in_sizes; (void)n_in; (void)out_size;

  hipMemsetAsync(d_ws, 0, zbytes, stream);

  int ebl = (N_EDGES + 255) / 256;
  int nbl = (N_NODES + 255) / 256;
  k_deg<<<ebl, 256, 0, stream>>>(src, dst, deg_out, deg_in);
  k_norm<<<nbl, 256, 0, stream>>>(deg_out, deg_in, norm_o, norm_i);
  k_scan1<<<nbl, 256, 0, stream>>>(deg_in, partial);
  k_scan2<<<1, 256, 0, stream>>>(partial, chunk_off, row_start, nbl);
  k_scan3<<<nbl, 256, 0, stream>>>(deg_in, chunk_off, row_start);
  k_fill<<<ebl, 256, 0, stream>>>(src, dst, row_start, cursor, csr_src, csr_eid);
  k_wt<<<dim3(8, 8, 2 * DEPTH), 256, 0, stream>>>(Wc1, Wc2, Wt);
  k_z<<<(N_NODES * 32 + 255) / 256, 256, 0, stream>>>(a_t, c_t, x_t, norm_o, zpack);
  k_in<<<N_NODES / 4, 256, 0, stream>>>(zpack, e_t, csr_src, csr_eid, row_start,
                                        norm_o, norm_i, W_in, b_in, W_e, b_e, hf, Af0);
  int gbl = N_NODES / 16;  // 3125, exact
  for (int d = 0; d < DEPTH; ++d) {
    // ping-pong: Af0 -> Af1 -> Af0 (read and write buffers must differ)
    k_layer<0><<<gbl, 256, 0, stream>>>(Af0, csr_src, row_start, Wt + (size_t)(2 * d) * HID * HID,
                                        norm_i, norm_o, bc1 + d * HID, g1 + d * HID, be1 + d * HID, hf, Af1);
    k_layer<1><<<gbl, 256, 0, stream>>>(Af1, csr_src, row_start, Wt + (size_t)(2 * d + 1) * HID * HID,
                                        norm_i, norm_o, bc2 + d * HID, g2 + d * HID, be2 + d * HID, hf, Af0);
  }
  k_poolhead<<<N_GRAPH, 256, 0, stream>>>(hf, gid, W_head, b_head, out);
}

// Round 6
// 1433.642 us; speedup vs baseline: 1.5552x; 1.0413x over previous
//
#include <hip/hip_runtime.h>
#include <hip/hip_bf16.h>

#define N_NODES 50000
#define N_EDGES 400000
#define N_GRAPH 256
#define HID 256
#define DEPTH 6

typedef float f32x4 __attribute__((ext_vector_type(4)));
typedef int   i32x4 __attribute__((ext_vector_type(4)));

__device__ __forceinline__ float bf2f(unsigned short u) {
  unsigned v = ((unsigned)u) << 16;
  return __builtin_bit_cast(float, v);
}
__device__ __forceinline__ unsigned short f2bf(float f) {
  unsigned u = __builtin_bit_cast(unsigned, f);
  u += 0x7fffu + ((u >> 16) & 1u);  // RNE
  return (unsigned short)(u >> 16);
}

__device__ __forceinline__ float block_sum256(float v, float* lds) {
#pragma unroll
  for (int off = 32; off > 0; off >>= 1) v += __shfl_down(v, off, 64);
  int w = threadIdx.x >> 6;
  if ((threadIdx.x & 63) == 0) lds[w] = v;
  __syncthreads();
  float r = lds[0] + lds[1] + lds[2] + lds[3];
  __syncthreads();
  return r;
}

__global__ __launch_bounds__(256) void k_deg(const int* __restrict__ src, const int* __restrict__ dst,
                                             int* deg_out, int* deg_in) {
  int e = blockIdx.x * 256 + threadIdx.x;
  if (e < N_EDGES) { atomicAdd(&deg_out[src[e]], 1); atomicAdd(&deg_in[dst[e]], 1); }
}

__global__ __launch_bounds__(256) void k_norm(const int* deg_out, const int* deg_in,
                                              float* norm_o, float* norm_i) {
  int i = blockIdx.x * 256 + threadIdx.x;
  if (i < N_NODES) {
    int dO = deg_out[i], dI = deg_in[i];
    norm_o[i] = dO > 0 ? rsqrtf((float)dO) : 0.f;
    norm_i[i] = dI > 0 ? rsqrtf((float)dI) : 0.f;
  }
}

__global__ __launch_bounds__(256) void k_scan1(const int* deg_in, int* partial) {
  int i = blockIdx.x * 256 + threadIdx.x;
  int v = (i < N_NODES) ? deg_in[i] : 0;
#pragma unroll
  for (int off = 32; off > 0; off >>= 1) v += __shfl_down(v, off, 64);
  __shared__ int l[4];
  if ((threadIdx.x & 63) == 0) l[threadIdx.x >> 6] = v;
  __syncthreads();
  if (threadIdx.x == 0) partial[blockIdx.x] = l[0] + l[1] + l[2] + l[3];
}

__global__ __launch_bounds__(256) void k_scan2(const int* partial, int* chunk_off, int* row_start, int nb) {
  __shared__ int ss[256];
  int t = threadIdx.x;
  int v = (t < nb) ? partial[t] : 0;
  ss[t] = v; __syncthreads();
#pragma unroll
  for (int off = 1; off < 256; off <<= 1) {
    int x = ss[t];
    int y = (t >= off) ? ss[t - off] : 0;
    __syncthreads();
    ss[t] = x + y;
    __syncthreads();
  }
  if (t < nb) chunk_off[t] = ss[t] - v;
  if (t == 0) row_start[N_NODES] = N_EDGES;
}

__global__ __launch_bounds__(256) void k_scan3(const int* deg_in, const int* chunk_off, int* row_start) {
  __shared__ int ss[256];
  int t = threadIdx.x;
  int i = blockIdx.x * 256 + t;
  int v = (i < N_NODES) ? deg_in[i] : 0;
  ss[t] = v; __syncthreads();
#pragma unroll
  for (int off = 1; off < 256; off <<= 1) {
    int x = ss[t];
    int y = (t >= off) ? ss[t - off] : 0;
    __syncthreads();
    ss[t] = x + y;
    __syncthreads();
  }
  if (i < N_NODES) row_start[i] = chunk_off[blockIdx.x] + ss[t] - v;
}

__global__ __launch_bounds__(256) void k_fill(const int* src, const int* dst, const int* row_start,
                                              int* cursor, int* csr_src, int* csr_eid) {
  int e = blockIdx.x * 256 + threadIdx.x;
  if (e < N_EDGES) {
    int d = dst[e];
    int p = atomicAdd(&cursor[d], 1);
    int pos = row_start[d] + p;
    csr_src[pos] = src[e];
    csr_eid[pos] = e;
  }
}

// Transpose + bf16-convert all 12 layer weights: Wt[li][n][k] = W[li][k][n]
__global__ __launch_bounds__(256) void k_wt(const float* __restrict__ Wc1, const float* __restrict__ Wc2,
                                            unsigned short* __restrict__ Wt) {
  __shared__ float tile[32][33];
  int li = blockIdx.z;
  const float* W = ((li & 1) ? Wc2 : Wc1) + (size_t)(li >> 1) * HID * HID;
  int k0 = blockIdx.x * 32, n0 = blockIdx.y * 32;
  int tx = threadIdx.x & 31, ty = threadIdx.x >> 5;
#pragma unroll
  for (int r = ty; r < 32; r += 8) tile[r][tx] = W[(size_t)(k0 + r) * HID + n0 + tx];
  __syncthreads();
  unsigned short* outp = Wt + (size_t)li * HID * HID;
#pragma unroll
  for (int r = ty; r < 32; r += 8) outp[(size_t)(n0 + r) * HID + k0 + tx] = f2bf(tile[tx][r]);
}

// Pack z[n][32] = concat(a,c,x)[27] * norm_o[n]  (pad to 32 f32, lanes 27..31 = 0)
__global__ __launch_bounds__(256) void k_z(const float* __restrict__ a, const float* __restrict__ c,
                                           const float* __restrict__ x, const float* __restrict__ norm_o,
                                           float* __restrict__ z) {
  int t = blockIdx.x * 256 + threadIdx.x;
  int n = t >> 5, lane = t & 31;
  if (n >= N_NODES) return;
  float v = 0.f;
  if (lane < 16) v = a[(size_t)n * 16 + lane];
  else if (lane < 24) v = c[(size_t)n * 8 + (lane - 16)];
  else if (lane < 27) v = x[(size_t)n * 3 + (lane - 24)];
  z[(size_t)n * 32 + lane] = v * norm_o[n];
}

// Input layer fused: aggregate packed z rows (lanes 0..31) + e_t rows (lanes 32..47),
// 4-deep edge unroll for MLP; K=43 matvec epilogue -> hf, Af.
__global__ __launch_bounds__(256) void k_in(const float* __restrict__ z, const float* __restrict__ e_t,
                                            const int* __restrict__ csr_src, const int* __restrict__ csr_eid,
                                            const int* __restrict__ rs, const float* __restrict__ norm_o,
                                            const float* __restrict__ norm_i, const float* __restrict__ W_in,
                                            const float* __restrict__ b_in, const float* __restrict__ W_e,
                                            const float* __restrict__ b_e, float* __restrict__ hf,
                                            unsigned short* __restrict__ Af) {
  int w = threadIdx.x >> 6, lane = threadIdx.x & 63;
  int n = blockIdx.x * 4 + w;  // 50000 % 4 == 0
  __shared__ float zs[4][48];
  int beg = rs[n], end = rs[n + 1];
  float acc = 0.f;
  int p = beg;
  if (lane < 32) {
    const float* zb = z + lane;
    for (; p + 4 <= end; p += 4) {
      int s0 = csr_src[p], s1 = csr_src[p + 1], s2 = csr_src[p + 2], s3 = csr_src[p + 3];
      float v0 = zb[(size_t)s0 * 32], v1 = zb[(size_t)s1 * 32];
      float v2 = zb[(size_t)s2 * 32], v3 = zb[(size_t)s3 * 32];
      acc += (v0 + v1) + (v2 + v3);
    }
    for (; p < end; ++p) acc += zb[(size_t)csr_src[p] * 32];
  } else if (lane < 48) {
    const float* eb = e_t + (lane - 32);
    for (; p + 4 <= end; p += 4) {
      int e0 = csr_eid[p], e1 = csr_eid[p + 1], e2 = csr_eid[p + 2], e3 = csr_eid[p + 3];
      float v0 = eb[(size_t)e0 * 16], v1 = eb[(size_t)e1 * 16];
      float v2 = eb[(size_t)e2 * 16], v3 = eb[(size_t)e3 * 16];
      acc += (v0 + v1) + (v2 + v3);
    }
    for (; p < end; ++p) acc += eb[(size_t)csr_eid[p] * 16];
  }
  if (lane < 48) zs[w][lane] = acc;
  __syncthreads();
  float degf = (float)(end - beg);
  float invd = 1.f / fmaxf(degf, 1.f);
  float niv = norm_i[n], nov = norm_o[n];
#pragma unroll
  for (int i = 0; i < 4; ++i) {
    int ch = lane + 64 * i;
    float da = 0.f, de = 0.f;
#pragma unroll
    for (int k = 0; k < 27; ++k) da += zs[w][k] * W_in[k * HID + ch];
#pragma unroll
    for (int k = 0; k < 16; ++k) de += zs[w][32 + k] * W_e[k * HID + ch];
    float val = da * niv + b_in[ch] + (de + degf * b_e[ch]) * invd;
    hf[(size_t)n * HID + ch] = val;
    Af[(size_t)n * HID + ch] = f2bf(val * nov);
  }
}

// Fused layer, 16-row tile (grid 3125): each wave gathers 4 node rows into LDS
// (8-deep edge unroll for MLP), then computes the 64-col slice of the
// [16,256]@[256,256] GEMM; epilogue norm_i+b -> LN -> SiLU -> (+res) -> AfN.
// Af / AfN must be distinct buffers (inter-block WAR race).
template <int RES>
__global__ __launch_bounds__(256) void k_layer(const unsigned short* __restrict__ Af,
                                               const int* __restrict__ csr_src, const int* __restrict__ rs,
                                               const unsigned short* __restrict__ Bt,
                                               const float* __restrict__ norm_i,
                                               const float* __restrict__ norm_o,
                                               const float* __restrict__ b, const float* __restrict__ g,
                                               const float* __restrict__ be, float* __restrict__ hf,
                                               unsigned short* __restrict__ AfN) {
  const int LDA = HID + 8;  // pad: keeps ds_read_b128 A-frags at <=2-way (free)
  __shared__ unsigned short As[16 * LDA];
  __shared__ float red1[4][16], red2[4][16];
  int wave = threadIdx.x >> 6, lane = threadIdx.x & 63;
  int l15 = lane & 15, quad = lane >> 4;
  int n0 = blockIdx.x * 16;  // 50000 = 16 * 3125, exact
  int off = lane * 4;
  // ---- gather: wave fills rows [wave*4, wave*4+4) of As ----
  for (int i = 0; i < 4; ++i) {
    int r = wave * 4 + i;
    int beg = rs[n0 + r], end = rs[n0 + r + 1];
    float a0 = 0.f, a1 = 0.f, a2 = 0.f, a3 = 0.f;
    int p = beg;
    for (; p + 8 <= end; p += 8) {
      int s[8];
#pragma unroll
      for (int q = 0; q < 8; ++q) s[q] = csr_src[p + q];
      ushort4 rr[8];
#pragma unroll
      for (int q = 0; q < 8; ++q) rr[q] = *(const ushort4*)(Af + (size_t)s[q] * HID + off);
#pragma unroll
      for (int q = 0; q < 8; ++q) {
        a0 += bf2f(rr[q].x); a1 += bf2f(rr[q].y); a2 += bf2f(rr[q].z); a3 += bf2f(rr[q].w);
      }
    }
    for (; p + 4 <= end; p += 4) {
      int s0 = csr_src[p], s1 = csr_src[p + 1], s2 = csr_src[p + 2], s3 = csr_src[p + 3];
      ushort4 r0 = *(const ushort4*)(Af + (size_t)s0 * HID + off);
      ushort4 r1 = *(const ushort4*)(Af + (size_t)s1 * HID + off);
      ushort4 r2 = *(const ushort4*)(Af + (size_t)s2 * HID + off);
      ushort4 r3 = *(const ushort4*)(Af + (size_t)s3 * HID + off);
      a0 += bf2f(r0.x) + bf2f(r1.x) + bf2f(r2.x) + bf2f(r3.x);
      a1 += bf2f(r0.y) + bf2f(r1.y) + bf2f(r2.y) + bf2f(r3.y);
      a2 += bf2f(r0.z) + bf2f(r1.z) + bf2f(r2.z) + bf2f(r3.z);
      a3 += bf2f(r0.w) + bf2f(r1.w) + bf2f(r2.w) + bf2f(r3.w);
    }
    for (; p < end; ++p) {
      int s0 = csr_src[p];
      ushort4 r0 = *(const ushort4*)(Af + (size_t)s0 * HID + off);
      a0 += bf2f(r0.x); a1 += bf2f(r0.y); a2 += bf2f(r0.z); a3 += bf2f(r0.w);
    }
    ushort4 o;
    o.x = f2bf(a0); o.y = f2bf(a1); o.z = f2bf(a2); o.w = f2bf(a3);
    *(ushort4*)(&As[(size_t)r * LDA + off]) = o;
  }
  __syncthreads();
  // ---- GEMM: wave covers cols [wave*64, wave*64+64), rows n0..n0+15 ----
  const unsigned short* asp = &As[(size_t)l15 * LDA + quad * 8];
  const unsigned short* bp = Bt + (size_t)(wave * 64 + l15) * HID + quad * 8;
  f32x4 acc[4] = {};
  asm volatile("s_nop 7\n\ts_nop 7" : "+v"(acc[0]), "+v"(acc[1]), "+v"(acc[2]), "+v"(acc[3]));
#pragma unroll
  for (int k0 = 0; k0 < HID; k0 += 32) {
    i32x4 af = *(const i32x4*)(asp + k0);
#pragma unroll
    for (int t = 0; t < 4; ++t) {
      i32x4 bt = *(const i32x4*)(bp + (size_t)t * 16 * HID + k0);
      asm volatile("v_mfma_f32_16x16x32_bf16 %0, %1, %2, %0" : "+v"(acc[t]) : "v"(af), "v"(bt));
    }
  }
  asm volatile("s_nop 7\n\ts_nop 7\n\ts_nop 7"
               : "+v"(acc[0]), "+v"(acc[1]), "+v"(acc[2]), "+v"(acc[3]));
  // C/D layout: col (within slice) = t*16 + l15, row = quad*4 + j
  float ni[4];
#pragma unroll
  for (int j = 0; j < 4; ++j) ni[j] = norm_i[n0 + quad * 4 + j];
#pragma unroll
  for (int t = 0; t < 4; ++t) {
    int ct = wave * 64 + t * 16 + l15;
    float bv = b[ct];
#pragma unroll
    for (int j = 0; j < 4; ++j) acc[t][j] = acc[t][j] * ni[j] + bv;
  }
  float s1[4] = {0.f, 0.f, 0.f, 0.f}, s2[4] = {0.f, 0.f, 0.f, 0.f};
#pragma unroll
  for (int t = 0; t < 4; ++t)
#pragma unroll
    for (int j = 0; j < 4; ++j) { s1[j] += acc[t][j]; s2[j] += acc[t][j] * acc[t][j]; }
#pragma unroll
  for (int m = 1; m < 16; m <<= 1) {
#pragma unroll
    for (int j = 0; j < 4; ++j) {
      s1[j] += __shfl_xor(s1[j], m, 16);
      s2[j] += __shfl_xor(s2[j], m, 16);
    }
  }
  if (l15 == 0) {
#pragma unroll
    for (int j = 0; j < 4; ++j) {
      red1[wave][quad * 4 + j] = s1[j];
      red2[wave][quad * 4 + j] = s2[j];
    }
  }
  __syncthreads();
  float mu[4], inv[4];
#pragma unroll
  for (int j = 0; j < 4; ++j) {
    int r = quad * 4 + j;
    float t1 = red1[0][r] + red1[1][r] + red1[2][r] + red1[3][r];
    float t2 = red2[0][r] + red2[1][r] + red2[2][r] + red2[3][r];
    mu[j] = t1 * (1.f / HID);
    float var = t2 * (1.f / HID) - mu[j] * mu[j];
    inv[j] = rsqrtf(var + 1e-5f);
  }
#pragma unroll
  for (int j = 0; j < 4; ++j) {
    int r = n0 + quad * 4 + j;
    float nov = norm_o[r];
    float* hrow = hf + (size_t)r * HID;
    unsigned short* an = AfN + (size_t)r * HID;
#pragma unroll
    for (int t = 0; t < 4; ++t) {
      int ct = wave * 64 + t * 16 + l15;
      float o = (acc[t][j] - mu[j]) * inv[j] * g[ct] + be[ct];
      float sl = o * (1.f / (1.f + __expf(-o)));
      float outv = sl;
      if (RES) {
        outv = sl + hrow[ct];
        hrow[ct] = outv;
      }
      an[ct] = f2bf(outv * nov);
    }
  }
}

// Fused mean-pool + head, no atomics: gid is sorted, one block per graph.
__global__ __launch_bounds__(256) void k_poolhead(const float* __restrict__ hf, const int* __restrict__ gid,
                                                  const float* __restrict__ Wh, const float* __restrict__ bh,
                                                  float* __restrict__ out) {
  int gg = blockIdx.x, ch = threadIdx.x;
  int lo = 0, hi = N_NODES;
  while (lo < hi) { int mid = (lo + hi) >> 1; if (gid[mid] < gg) lo = mid + 1; else hi = mid; }
  int beg = lo;
  hi = N_NODES;
  while (lo < hi) { int mid = (lo + hi) >> 1; if (gid[mid] < gg + 1) lo = mid + 1; else hi = mid; }
  int end = lo;
  float s = 0.f;
  int n = beg;
  for (; n + 4 <= end; n += 4) {
    s += hf[(size_t)n * HID + ch] + hf[(size_t)(n + 1) * HID + ch] +
         hf[(size_t)(n + 2) * HID + ch] + hf[(size_t)(n + 3) * HID + ch];
  }
  for (; n < end; ++n) s += hf[(size_t)n * HID + ch];
  float v = s * Wh[ch];
  __shared__ float l[4];
  float tot = block_sum256(v, l);
  if (ch == 0) {
    float c = fmaxf((float)(end - beg), 1.f);
    float xx = tot / c + bh[0];
    out[gg] = fmaxf(xx, 0.f) + log1pf(expf(-fabsf(xx)));  // stable softplus
  }
}

extern "C" void kernel_launch(void* const* d_in, const int* in_sizes, int n_in,
                              void* d_out, int out_size, void* d_ws, size_t ws_size,
                              hipStream_t stream) {
  const float* a_t = (const float*)d_in[0];
  const float* c_t = (const float*)d_in[1];
  const float* x_t = (const float*)d_in[2];
  const float* e_t = (const float*)d_in[3];
  const int* src = (const int*)d_in[4];
  const int* dst = (const int*)d_in[5];
  const int* gid = (const int*)d_in[6];
  const float* W_in = (const float*)d_in[7];
  const float* b_in = (const float*)d_in[8];
  const float* W_e  = (const float*)d_in[9];
  const float* b_e  = (const float*)d_in[10];
  const float* Wc1  = (const float*)d_in[11];
  const float* bc1  = (const float*)d_in[12];
  const float* g1   = (const float*)d_in[13];
  const float* be1  = (const float*)d_in[14];
  const float* Wc2  = (const float*)d_in[15];
  const float* bc2  = (const float*)d_in[16];
  const float* g2   = (const float*)d_in[17];
  const float* be2  = (const float*)d_in[18];
  const float* W_head = (const float*)d_in[19];
  const float* b_head = (const float*)d_in[20];
  float* out = (float*)d_out;

  char* base = (char*)d_ws;
  size_t off = 0;
  auto carve = [&](size_t bytes) -> void* {
    void* p = base + off;
    off += (bytes + 255) & ~(size_t)255;
    return p;
  };
  int*   deg_out = (int*)carve((size_t)N_NODES * 4);
  int*   deg_in  = (int*)carve((size_t)N_NODES * 4);
  int*   cursor  = (int*)carve((size_t)N_NODES * 4);
  size_t zbytes = off;  // zeroed each call
  float* norm_o  = (float*)carve((size_t)N_NODES * 4);
  float* norm_i  = (float*)carve((size_t)N_NODES * 4);
  int*   row_start = (int*)carve((size_t)(N_NODES + 1) * 4);
  int*   partial   = (int*)carve(256 * 4);
  int*   chunk_off = (int*)carve(256 * 4);
  int*   csr_src   = (int*)carve((size_t)N_EDGES * 4);
  int*   csr_eid   = (int*)carve((size_t)N_EDGES * 4);
  unsigned short* Wt = (unsigned short*)carve((size_t)2 * DEPTH * HID * HID * 2);
  float* zpack = (float*)carve((size_t)N_NODES * 32 * 4);
  float* hf = (float*)carve((size_t)N_NODES * HID * 4);
  unsigned short* Af0 = (unsigned short*)carve((size_t)N_NODES * HID * 2);
  unsigned short* Af1 = (unsigned short*)carve((size_t)N_NODES * HID * 2);
  (void)ws_size; (void)in_sizes; (void)n_in; (void)out_size;

  hipMemsetAsync(d_ws, 0, zbytes, stream);

  int ebl = (N_EDGES + 255) / 256;
  int nbl = (N_NODES + 255) / 256;
  k_deg<<<ebl, 256, 0, stream>>>(src, dst, deg_out, deg_in);
  k_norm<<<nbl, 256, 0, stream>>>(deg_out, deg_in, norm_o, norm_i);
  k_scan1<<<nbl, 256, 0, stream>>>(deg_in, partial);
  k_scan2<<<1, 256, 0, stream>>>(partial, chunk_off, row_start, nbl);
  k_scan3<<<nbl, 256, 0, stream>>>(deg_in, chunk_off, row_start);
  k_fill<<<ebl, 256, 0, stream>>>(src, dst, row_start, cursor, csr_src, csr_eid);
  k_wt<<<dim3(8, 8, 2 * DEPTH), 256, 0, stream>>>(Wc1, Wc2, Wt);
  k_z<<<(N_NODES * 32 + 255) / 256, 256, 0, stream>>>(a_t, c_t, x_t, norm_o, zpack);
  k_in<<<N_NODES / 4, 256, 0, stream>>>(zpack, e_t, csr_src, csr_eid, row_start,
                                        norm_o, norm_i, W_in, b_in, W_e, b_e, hf, Af0);
  int gbl = N_NODES / 16;  // 3125, exact
  for (int d = 0; d < DEPTH; ++d) {
    // ping-pong: Af0 -> Af1 -> Af0 (read and write buffers must differ)
    k_layer<0><<<gbl, 256, 0, stream>>>(Af0, csr_src, row_start, Wt + (size_t)(2 * d) * HID * HID,
                                        norm_i, norm_o, bc1 + d * HID, g1 + d * HID, be1 + d * HID, hf, Af1);
    k_layer<1><<<gbl, 256, 0, stream>>>(Af1, csr_src, row_start, Wt + (size_t)(2 * d + 1) * HID * HID,
                                        norm_i, norm_o, bc2 + d * HID, g2 + d * HID, be2 + d * HID, hf, Af0);
  }
  k_poolhead<<<N_GRAPH, 256, 0, stream>>>(hf, gid, W_head, b_head, out);
}